// Round 1
// baseline (743.439 us; speedup 1.0000x reference)
//
#include <hip/hip_runtime.h>
#include <math.h>

#define OLDV 50257
#define FINV 52257
#define NEWV 53257
#define DIM  2048
#define TTOK 32768
#define NNUMT 4096
#define HID  8192
#define NCHEB 16
#define NUNITS 6
#define NROWS 96            // NCHEB * NUNITS
#define RADIUS 5.5f

// ws layout (floats):
//   A      [96][8192]      @ 0         (786432)
//   Ppart  [16][96][2048]  @ 786432    (3145728)
//   P      [96][2048]      @ 3932160   (196608)
#define WS_A     0
#define WS_PPART 786432
#define WS_P     3932160
#define KCH 16
#define KPC 512             // K per split-K chunk; KCH*KPC == HID

__device__ __forceinline__ float gelu_exact(float x) {
    return 0.5f * x * (1.0f + erff(x * 0.70710678118654752f));
}

// A[(m*6+u)][k] = gelu(v_m * W1[0][k] + ue[u][0]*W1[1][k] + ue[u][1]*W1[2][k] + b1[k])
__global__ void build_A(const float* __restrict__ W1, const float* __restrict__ b1,
                        const float* __restrict__ uemb, float* __restrict__ A) {
    int idx = blockIdx.x * 256 + threadIdx.x;    // 96*8192 threads
    int k = idx & (HID - 1);
    int r = idx >> 13;
    int m = r / 6, u = r - 6 * m;
    float theta = (2.0f * (float)m + 1.0f) * (3.14159265358979f / (2.0f * NCHEB));
    float vm = RADIUS * cosf(theta);
    float e0 = uemb[u * 2 + 0], e1 = uemb[u * 2 + 1];
    float x = vm * W1[k] + e0 * W1[HID + k] + e1 * W1[2 * HID + k] + b1[k];
    A[r * HID + k] = gelu_exact(x);
}

// Ppart[kc][96][2048] partial of A[96][8192] @ W2[8192][2048] over K chunk kc
__global__ void __launch_bounds__(256) gemm_P(const float* __restrict__ A,
                                              const float* __restrict__ W2,
                                              float* __restrict__ Ppart) {
    __shared__ float As[32][NROWS + 1];   // [kk][r], pad to break stride-96 conflicts
    __shared__ float Ws[32][64];          // [kk][c]
    int ct = blockIdx.x;                  // 0..31  -> 64-col tile
    int kc = blockIdx.y;                  // 0..15  -> 512-K chunk
    int tid = threadIdx.x;
    int c0 = ct * 64;
    int kbase = kc * KPC;
    int tc = tid & 15, trr = tid >> 4;    // cols tc*4..+3, rows trr*6..+5
    float4 acc[6];
    #pragma unroll
    for (int i = 0; i < 6; ++i) acc[i] = make_float4(0.f, 0.f, 0.f, 0.f);

    int l8 = tid & 7;        // A staging: 8 threads per row (32 k each, float4)
    int rb = tid >> 3;       // 0..31
    int cw = (tid & 15) * 4; // W2 staging
    int kwb = tid >> 4;      // 0..15

    for (int kk0 = 0; kk0 < KPC; kk0 += 32) {
        #pragma unroll
        for (int it = 0; it < 3; ++it) {
            int r = it * 32 + rb;
            float4 a4 = *(const float4*)&A[(size_t)r * HID + kbase + kk0 + l8 * 4];
            As[l8 * 4 + 0][r] = a4.x;
            As[l8 * 4 + 1][r] = a4.y;
            As[l8 * 4 + 2][r] = a4.z;
            As[l8 * 4 + 3][r] = a4.w;
        }
        #pragma unroll
        for (int p = 0; p < 2; ++p) {
            int kw = p * 16 + kwb;
            *(float4*)&Ws[kw][cw] =
                *(const float4*)&W2[(size_t)(kbase + kk0 + kw) * DIM + c0 + cw];
        }
        __syncthreads();
        #pragma unroll
        for (int kk = 0; kk < 32; ++kk) {
            float4 w = *(float4*)&Ws[kk][tc * 4];
            #pragma unroll
            for (int i = 0; i < 6; ++i) {
                float a = As[kk][trr * 6 + i];
                acc[i].x += a * w.x; acc[i].y += a * w.y;
                acc[i].z += a * w.z; acc[i].w += a * w.w;
            }
        }
        __syncthreads();
    }
    #pragma unroll
    for (int i = 0; i < 6; ++i) {
        int r = trr * 6 + i;
        *(float4*)&Ppart[((size_t)kc * NROWS + r) * DIM + c0 + tc * 4] = acc[i];
    }
}

__global__ void reduce_P(const float* __restrict__ Ppart, float* __restrict__ P) {
    int idx = blockIdx.x * 256 + threadIdx.x;   // 96*2048 threads
    float s = 0.f;
    #pragma unroll
    for (int c = 0; c < KCH; ++c) s += Ppart[(size_t)c * (NROWS * DIM) + idx];
    P[idx] = s;
}

// out[t][:] = (id < OLD ? orig_emb[id] : new_emb[id-OLD]), vectorized float4
__global__ void gather_emb(const int* __restrict__ ids, const float4* __restrict__ orig,
                           const float4* __restrict__ newe, float4* __restrict__ out) {
    int g = blockIdx.x * 256 + threadIdx.x;     // TTOK * 512 threads
    int t = g >> 9;
    int c = g & 511;
    int id = ids[t];
    const float4* src = (id < OLDV) ? (orig + (size_t)id * 512 + c)
                                    : (newe + (size_t)(id - OLDV) * 512 + c);
    out[g] = *src;
}

// out[pos[i]][:] += b2 + sum_m lambda_m(v_i) * P[m*6+u_i][:]
__global__ void apply_mlp(const int* __restrict__ pos, const float* __restrict__ vals,
                          const int* __restrict__ units, const float* __restrict__ P,
                          const float* __restrict__ b2, float* __restrict__ out) {
    int i = blockIdx.x;
    float v = vals[i];
    v = fminf(fmaxf(v, -RADIUS), RADIUS);
    int u = units[i];
    size_t p = (size_t)pos[i];

    float lam[NCHEB];
    float den = 0.f;
    int hit = -1;
    #pragma unroll
    for (int m = 0; m < NCHEB; ++m) {
        float theta = (2.0f * (float)m + 1.0f) * (3.14159265358979f / (2.0f * NCHEB));
        float vm = RADIUS * cosf(theta);
        float wm = ((m & 1) ? -1.0f : 1.0f) * sinf(theta);
        float d = v - vm;
        if (fabsf(d) < 1e-6f) hit = m;
        float w = wm / d;
        lam[m] = w;
        den += w;
    }
    if (hit >= 0) {
        #pragma unroll
        for (int m = 0; m < NCHEB; ++m) lam[m] = (m == hit) ? 1.f : 0.f;
    } else {
        float inv = 1.0f / den;
        #pragma unroll
        for (int m = 0; m < NCHEB; ++m) lam[m] *= inv;
    }

    int tid = threadIdx.x;
    #pragma unroll
    for (int jj = 0; jj < DIM / 256; ++jj) {
        int j = tid + jj * 256;
        float s = b2[j];
        #pragma unroll
        for (int m = 0; m < NCHEB; ++m)
            s += lam[m] * P[(size_t)(m * 6 + u) * DIM + j];
        out[p * DIM + j] += s;
    }
}

extern "C" void kernel_launch(void* const* d_in, const int* in_sizes, int n_in,
                              void* d_out, int out_size, void* d_ws, size_t ws_size,
                              hipStream_t stream) {
    const int*   ids   = (const int*)d_in[0];
    const int*   npos  = (const int*)d_in[1];
    const float* nval  = (const float*)d_in[2];
    const int*   nunit = (const int*)d_in[3];
    const float* orig  = (const float*)d_in[4];
    const float* newe  = (const float*)d_in[5];
    const float* uemb  = (const float*)d_in[6];
    const float* W1    = (const float*)d_in[7];
    const float* b1    = (const float*)d_in[8];
    const float* W2    = (const float*)d_in[9];
    const float* b2    = (const float*)d_in[10];
    float* out = (float*)d_out;
    float* ws  = (float*)d_ws;

    float* A     = ws + WS_A;
    float* Ppart = ws + WS_PPART;
    float* P     = ws + WS_P;

    build_A<<<(NROWS * HID) / 256, 256, 0, stream>>>(W1, b1, uemb, A);
    gemm_P<<<dim3(32, 16), 256, 0, stream>>>(A, W2, Ppart);
    reduce_P<<<(NROWS * DIM) / 256, 256, 0, stream>>>(Ppart, P);
    gather_emb<<<(TTOK * (DIM / 4)) / 256, 256, 0, stream>>>(
        ids, (const float4*)orig, (const float4*)newe, (float4*)out);
    apply_mlp<<<NNUMT, 256, 0, stream>>>(npos, nval, nunit, P, b2, out);
}